// Round 3
// baseline (535.906 us; speedup 1.0000x reference)
//
#include <hip/hip_runtime.h>
#include <stdint.h>

// Problem constants
#define B_   8
#define C_   256
#define N_   16384   // 128*128 spatial

typedef __attribute__((ext_vector_type(8))) short bf16x8;
typedef __attribute__((ext_vector_type(4))) float f32x4;

__device__ inline float bf2f(unsigned short h) {
    return __uint_as_float(((unsigned)h) << 16);
}
__device__ inline unsigned short f2bf(float f) {
    unsigned u = __float_as_uint(f);
    u += 0x7FFF + ((u >> 16) & 1);   // round-to-nearest-even
    return (unsigned short)(u >> 16);
}
// monotone float<->uint key for atomicMax over floats
__device__ inline unsigned fkey(float f) {
    unsigned u = __float_as_uint(f);
    return (u & 0x80000000u) ? ~u : (u | 0x80000000u);
}
__device__ inline float funkey(unsigned k) {
    unsigned u = (k & 0x80000000u) ? (k ^ 0x80000000u) : ~k;
    return __uint_as_float(u);
}

// async global->LDS, 16B per lane. LDS dest = wave-uniform base + lane*16.
__device__ inline void gl_lds16(const void* g, void* l) {
    __builtin_amdgcn_global_load_lds(
        reinterpret_cast<const __attribute__((address_space(1))) unsigned int*>(
            reinterpret_cast<uintptr_t>(g)),
        reinterpret_cast<__attribute__((address_space(3))) unsigned int*>(
            reinterpret_cast<uintptr_t>(l)),
        16, 0, 0);
}

__device__ inline f32x4 mfma16(bf16x8 a, bf16x8 b, f32x4 c) {
    return __builtin_amdgcn_mfma_f32_16x16x32_bf16(a, b, c, 0, 0, 0);
}

// ---------------------------------------------------------------------------
// K1: x [B,C,N] fp32  ->  xT [B,N,C] bf16   (64x64 tiles through LDS)
// ---------------------------------------------------------------------------
__global__ __launch_bounds__(256) void k1_transpose(const float* __restrict__ x,
                                                    unsigned short* __restrict__ xT) {
    __shared__ unsigned short tile[64][65];
    const int b = blockIdx.z, c0 = blockIdx.y * 64, n0 = blockIdx.x * 64;
    const float* xb = x + (size_t)b * C_ * N_;
    const int t = threadIdx.x;
    const int tr = t >> 4, tc4 = (t & 15) * 4;
#pragma unroll
    for (int p = 0; p < 4; p++) {
        const int i = p * 16 + tr;   // c index
        const float4 v = *(const float4*)(xb + (size_t)(c0 + i) * N_ + n0 + tc4);
        tile[i][tc4 + 0] = f2bf(v.x);
        tile[i][tc4 + 1] = f2bf(v.y);
        tile[i][tc4 + 2] = f2bf(v.z);
        tile[i][tc4 + 3] = f2bf(v.w);
    }
    __syncthreads();
    unsigned short* xTb = xT + (size_t)b * N_ * C_;
#pragma unroll
    for (int p = 0; p < 4; p++) {
        const int jj = p * 16 + tr;  // n index
        ushort4 o;
        o.x = tile[tc4 + 0][jj];
        o.y = tile[tc4 + 1][jj];
        o.z = tile[tc4 + 2][jj];
        o.w = tile[tc4 + 3][jj];
        *(ushort4*)(xTb + (size_t)(n0 + jj) * C_ + c0 + tc4) = o;
    }
}

// ---------------------------------------------------------------------------
// K1b: convert w_qkv -> bf16 (blocks 0..191), block 192 computes BN constants
// ---------------------------------------------------------------------------
__global__ __launch_bounds__(256) void k1b_setup(const float* __restrict__ wqkv,
                                                 const float* __restrict__ gamma,
                                                 const float* __restrict__ beta,
                                                 const float* __restrict__ rmean,
                                                 const float* __restrict__ rvar,
                                                 unsigned short* __restrict__ wqkv_bf,
                                                 float* __restrict__ inv,
                                                 float* __restrict__ b2) {
    const int t = threadIdx.x;
    if (blockIdx.x < 192) {
        const int base = blockIdx.x * 1024 + t * 4;
        const float4 v = *(const float4*)(wqkv + base);
        ushort4 o;
        o.x = f2bf(v.x); o.y = f2bf(v.y); o.z = f2bf(v.z); o.w = f2bf(v.w);
        *(ushort4*)(wqkv_bf + base) = o;
    } else {
        const float iv = gamma[t] * rsqrtf(rvar[t] + 1e-5f);
        inv[t] = iv;
        b2[t]  = beta[t] - rmean[t] * iv;
    }
}

// ---------------------------------------------------------------------------
// K2: KV GEMM, B-resident variant.
//   Bs = xT tile [128 n][256 k] bf16 = 64 KB, staged ONCE via gl_lds16.
//   A  = Wkv [512,256] bf16, fragments loaded straight from global (L2-hot).
//   Loop 4 m-chunks of 128; rows 0..255 -> k logits (+atomicMax row max),
//   rows 256..511 -> v.  NO barriers inside the K-loop.
// grid (128 n-tiles, 8 batches), 256 thr
// ---------------------------------------------------------------------------
__global__ __launch_bounds__(256) void k2_kv(const unsigned short* __restrict__ Wkv,
                                             const unsigned short* __restrict__ xT,
                                             unsigned short* __restrict__ kL,
                                             unsigned short* __restrict__ vv,
                                             unsigned int* __restrict__ rmaxU) {
    __shared__ __align__(16) unsigned short Bs[128 * 256];  // 64 KB
    const int b  = blockIdx.y;
    const int n0 = blockIdx.x * 128;
    const int t = threadIdx.x, wave = t >> 6, lane = t & 63;
    const int wm = wave >> 1, wn = wave & 1;

    const unsigned short* xTb = xT + (size_t)b * N_ * C_ + (size_t)n0 * C_;  // 64 KB contiguous
#pragma unroll
    for (int rnd = 0; rnd < 16; rnd++) {
        gl_lds16(xTb + rnd * 2048 + wave * 512 + lane * 8,
                 Bs + rnd * 2048 + wave * 512);
    }
    __syncthreads();   // waits vmcnt(0): Bs fully staged; read-only afterwards

    const int fr = lane & 15;
    const int fk = (lane >> 4) * 8;
    const int col = lane & 15, rowq = (lane >> 4) * 4;
    unsigned short* outK = kL + (size_t)b * C_ * N_;
    unsigned short* outV = vv + (size_t)b * C_ * N_;

    for (int mc = 0; mc < 4; mc++) {
        const int mbase = mc * 128;
        f32x4 acc[4][4];
#pragma unroll
        for (int i = 0; i < 4; i++)
#pragma unroll
            for (int j = 0; j < 4; j++)
#pragma unroll
                for (int r = 0; r < 4; r++) acc[i][j][r] = 0.f;

#pragma unroll
        for (int kk = 0; kk < 256; kk += 32) {
            bf16x8 af[4], bfv[4];
#pragma unroll
            for (int i = 0; i < 4; i++)
                af[i] = *(const bf16x8*)(Wkv + (size_t)(mbase + wm * 64 + i * 16 + fr) * 256 + kk + fk);
#pragma unroll
            for (int j = 0; j < 4; j++)
                bfv[j] = *(const bf16x8*)(Bs + (wn * 64 + j * 16 + fr) * 256 + kk + fk);
#pragma unroll
            for (int i = 0; i < 4; i++)
#pragma unroll
                for (int j = 0; j < 4; j++)
                    acc[i][j] = mfma16(af[i], bfv[j], acc[i][j]);
        }

        if (mc < 2) {
            // k-logit rows: store bf16 + per-row max (over this n-tile) -> atomicMax
#pragma unroll
            for (int i = 0; i < 4; i++) {
                const int gm = mbase + wm * 64 + i * 16 + rowq;
#pragma unroll
                for (int r = 0; r < 4; r++) {
                    float vmax = -3.4e38f;
#pragma unroll
                    for (int j = 0; j < 4; j++) {
                        const int gn = n0 + wn * 64 + j * 16 + col;
                        const unsigned short hv = f2bf(acc[i][j][r]);
                        outK[(size_t)(gm + r) * N_ + gn] = hv;
                        vmax = fmaxf(vmax, bf2f(hv));
                    }
#pragma unroll
                    for (int o = 1; o < 16; o <<= 1)
                        vmax = fmaxf(vmax, __shfl_xor(vmax, o, 64));
                    if (col == 0)
                        atomicMax(&rmaxU[b * 256 + gm + r], fkey(vmax));
                }
            }
        } else {
#pragma unroll
            for (int i = 0; i < 4; i++) {
                const int gm = mbase - 256 + wm * 64 + i * 16 + rowq;
#pragma unroll
                for (int j = 0; j < 4; j++) {
                    const int gn = n0 + wn * 64 + j * 16 + col;
#pragma unroll
                    for (int r = 0; r < 4; r++)
                        outV[(size_t)(gm + r) * N_ + gn] = f2bf(acc[i][j][r]);
                }
            }
        }
    }
}

// ---------------------------------------------------------------------------
// K4: ctx_raw[b,c,d] += sum_n exp(k[c,n]-max_c) * v[d,n].  Split-K over n
//     (8 chunks of 2048), fp32 atomicAdd.  Also accumulates rsum[b,c] =
//     sum_n exp(k[c,n]-max_c)  (gated to blockIdx.x==0 blocks).
// grid (2,2, B*8)
// ---------------------------------------------------------------------------
__global__ __launch_bounds__(256) void k4_ctx(const unsigned short* __restrict__ kL,
                                              const unsigned short* __restrict__ v,
                                              const unsigned int* __restrict__ rmaxU,
                                              float* __restrict__ ctx,
                                              float* __restrict__ rsum) {
    __shared__ __align__(16) unsigned short As[128 * 32];
    __shared__ __align__(16) unsigned short Bs[128 * 32];
    const int bz = blockIdx.z;
    const int b = bz >> 3, s = bz & 7;
    const int m0 = blockIdx.y * 128;   // c rows
    const int n0 = blockIdx.x * 128;   // d rows
    const int t = threadIdx.x, wave = t >> 6, lane = t & 63;
    const int wm = wave >> 1, wn = wave & 1;

    const unsigned short* kb = kL + (size_t)b * C_ * N_;
    const unsigned short* vb = v  + (size_t)b * C_ * N_;

    const int ch1 = wave * 64 + lane, ch2 = ch1 + 256;
    const int r1 = ch1 >> 2, q1 = ch1 & 3;
    const int r2 = ch2 >> 2, q2 = ch2 & 3;
    const float mx1 = funkey(rmaxU[b * 256 + m0 + r1]);
    const float mx2 = funkey(rmaxU[b * 256 + m0 + r2]);
    unsigned short* ldsB1 = Bs + wave * 512;
    unsigned short* ldsB2 = Bs + 2048 + wave * 512;

    f32x4 acc[4][4];
#pragma unroll
    for (int i = 0; i < 4; i++)
#pragma unroll
        for (int j = 0; j < 4; j++)
#pragma unroll
            for (int r = 0; r < 4; r++) acc[i][j][r] = 0.f;

    float sacc1 = 0.f, sacc2 = 0.f;
    const int fr = lane & 15;
    const int fk = (lane >> 4) * 8;
    const int kbase = s * 2048;

    for (int kk = kbase; kk < kbase + 2048; kk += 32) {
        __syncthreads();
        gl_lds16(vb + (size_t)(n0 + r1) * N_ + kk + q1 * 8, ldsB1);
        gl_lds16(vb + (size_t)(n0 + r2) * N_ + kk + q2 * 8, ldsB2);
        const uint4 a1 = *(const uint4*)(kb + (size_t)(m0 + r1) * N_ + kk + q1 * 8);
        const uint4 a2 = *(const uint4*)(kb + (size_t)(m0 + r2) * N_ + kk + q2 * 8);
        uint4 e1, e2;
        {
            const unsigned short* p = (const unsigned short*)&a1;
            unsigned short* o = (unsigned short*)&e1;
#pragma unroll
            for (int e = 0; e < 8; e++) {
                const float ev = __expf(bf2f(p[e]) - mx1);
                sacc1 += ev;
                o[e] = f2bf(ev);
            }
        }
        {
            const unsigned short* p = (const unsigned short*)&a2;
            unsigned short* o = (unsigned short*)&e2;
#pragma unroll
            for (int e = 0; e < 8; e++) {
                const float ev = __expf(bf2f(p[e]) - mx2);
                sacc2 += ev;
                o[e] = f2bf(ev);
            }
        }
        *(uint4*)(As + r1 * 32 + q1 * 8) = e1;
        *(uint4*)(As + r2 * 32 + q2 * 8) = e2;
        __syncthreads();
        bf16x8 af[4], bfv[4];
#pragma unroll
        for (int i = 0; i < 4; i++)
            af[i] = *(const bf16x8*)(As + (wm * 64 + i * 16 + fr) * 32 + fk);
#pragma unroll
        for (int j = 0; j < 4; j++)
            bfv[j] = *(const bf16x8*)(Bs + (wn * 64 + j * 16 + fr) * 32 + fk);
#pragma unroll
        for (int i = 0; i < 4; i++)
#pragma unroll
            for (int j = 0; j < 4; j++)
                acc[i][j] = mfma16(af[i], bfv[j], acc[i][j]);
    }

    // rsum contribution: rows r1 (= t>>2) and r2 (= r1+64) of this (m0, s) chunk.
    // Each row's 32-k-chunk is covered by 4 threads (q = lane&3). Avoid the
    // n0-duplicate by gating to blockIdx.x == 0.
    if (blockIdx.x == 0) {
        sacc1 += __shfl_xor(sacc1, 1, 64);
        sacc1 += __shfl_xor(sacc1, 2, 64);
        sacc2 += __shfl_xor(sacc2, 1, 64);
        sacc2 += __shfl_xor(sacc2, 2, 64);
        if ((lane & 3) == 0) {
            atomicAdd(&rsum[b * 256 + m0 + r1], sacc1);
            atomicAdd(&rsum[b * 256 + m0 + r2], sacc2);
        }
    }

    float* cb = ctx + (size_t)b * C_ * C_;
    const int col = lane & 15, rowq = (lane >> 4) * 4;
#pragma unroll
    for (int i = 0; i < 4; i++) {
        const int gc = m0 + wm * 64 + i * 16 + rowq;
#pragma unroll
        for (int j = 0; j < 4; j++) {
            const int gd = n0 + wn * 64 + j * 16 + col;
#pragma unroll
            for (int r = 0; r < 4; r++)
                atomicAdd(&cb[(size_t)(gc + r) * C_ + gd], acc[i][j][r]);
        }
    }
}

// ---------------------------------------------------------------------------
// K5a: T[b,o,c] = (sum_d Wp[o,d]*ctx[b,c,d]) / rsum[b,c]   (fp32 tiled)
// grid (4,4,8) : 64x64 tiles
// ---------------------------------------------------------------------------
__global__ __launch_bounds__(256) void k5a_T(const float* __restrict__ Wp,
                                             const float* __restrict__ ctx,
                                             const float* __restrict__ rsum,
                                             float* __restrict__ T) {
    __shared__ float Asm[64][65];
    __shared__ float Bsm[64][65];
    const int b = blockIdx.z;
    const int o0 = blockIdx.y * 64, c0 = blockIdx.x * 64;
    const int t = threadIdx.x;
    const int tm = t >> 4, tn = t & 15;
    const int lc4 = tn * 4;
    float acc[4][4] = {};
    const float* cb = ctx + (size_t)b * C_ * C_;
    for (int kk = 0; kk < 256; kk += 64) {
        __syncthreads();
#pragma unroll
        for (int p = 0; p < 4; p++) {
            const int r = p * 16 + tm;
            const float4 av = *(const float4*)(Wp + (size_t)(o0 + r) * C_ + kk + lc4);
            Asm[r][lc4] = av.x; Asm[r][lc4 + 1] = av.y; Asm[r][lc4 + 2] = av.z; Asm[r][lc4 + 3] = av.w;
            const float4 bv = *(const float4*)(cb + (size_t)(c0 + r) * C_ + kk + lc4);
            Bsm[r][lc4] = bv.x; Bsm[r][lc4 + 1] = bv.y; Bsm[r][lc4 + 2] = bv.z; Bsm[r][lc4 + 3] = bv.w;
        }
        __syncthreads();
        for (int k = 0; k < 64; k++) {
            float a_[4], b_[4];
#pragma unroll
            for (int i = 0; i < 4; i++) a_[i] = Asm[tm * 4 + i][k];
#pragma unroll
            for (int j = 0; j < 4; j++) b_[j] = Bsm[tn * 4 + j][k];
#pragma unroll
            for (int i = 0; i < 4; i++)
#pragma unroll
                for (int j = 0; j < 4; j++) acc[i][j] += a_[i] * b_[j];
        }
    }
    float isv[4];
#pragma unroll
    for (int j = 0; j < 4; j++) isv[j] = 1.f / rsum[b * 256 + c0 + tn * 4 + j];
#pragma unroll
    for (int i = 0; i < 4; i++)
#pragma unroll
        for (int j = 0; j < 4; j++)
            T[((size_t)b * C_ + o0 + tm * 4 + i) * C_ + c0 + tn * 4 + j] = acc[i][j] * isv[j];
}

// ---------------------------------------------------------------------------
// K5b: G[b,o,j] = inv[o] * sum_c T[b,o,c]*Wq[c,j]   -> bf16  (fp32 tiled)
// grid (4,4,8)
// ---------------------------------------------------------------------------
__global__ __launch_bounds__(256) void k5b_G(const float* __restrict__ Tm,
                                             const float* __restrict__ Wq,
                                             const float* __restrict__ inv,
                                             unsigned short* __restrict__ G) {
    __shared__ float Asm[64][65];   // T rows o, cols c (k)
    __shared__ float Bsm[64][65];   // Wq rows c (k), cols j
    const int b = blockIdx.z;
    const int o0 = blockIdx.y * 64, j0 = blockIdx.x * 64;
    const int t = threadIdx.x;
    const int tm = t >> 4, tn = t & 15;
    const int lc4 = tn * 4;
    float acc[4][4] = {};
    const float* Tb = Tm + (size_t)b * C_ * C_;
    for (int kk = 0; kk < 256; kk += 64) {
        __syncthreads();
#pragma unroll
        for (int p = 0; p < 4; p++) {
            const int r = p * 16 + tm;
            const float4 av = *(const float4*)(Tb + (size_t)(o0 + r) * C_ + kk + lc4);
            Asm[r][lc4] = av.x; Asm[r][lc4 + 1] = av.y; Asm[r][lc4 + 2] = av.z; Asm[r][lc4 + 3] = av.w;
            const float4 bv = *(const float4*)(Wq + (size_t)(kk + r) * C_ + j0 + lc4);
            Bsm[r][lc4] = bv.x; Bsm[r][lc4 + 1] = bv.y; Bsm[r][lc4 + 2] = bv.z; Bsm[r][lc4 + 3] = bv.w;
        }
        __syncthreads();
        for (int k = 0; k < 64; k++) {
            float a_[4], b_[4];
#pragma unroll
            for (int i = 0; i < 4; i++) a_[i] = Asm[tm * 4 + i][k];
#pragma unroll
            for (int j = 0; j < 4; j++) b_[j] = Bsm[k][tn * 4 + j];
#pragma unroll
            for (int i = 0; i < 4; i++)
#pragma unroll
                for (int j = 0; j < 4; j++) acc[i][j] += a_[i] * b_[j];
        }
    }
#pragma unroll
    for (int i = 0; i < 4; i++) {
        const float iv = inv[o0 + tm * 4 + i];
#pragma unroll
        for (int j = 0; j < 4; j++)
            G[((size_t)b * C_ + o0 + tm * 4 + i) * C_ + j0 + tn * 4 + j] = f2bf(acc[i][j] * iv);
    }
}

// ---------------------------------------------------------------------------
// K6: out[b,o,n] = relu( sum_j G[b,o,j]*xT[b,n,j] + b2[o] )  fp32 out
//   B-resident variant: Bs = xT tile [128 n][256 j] = 64 KB staged once;
//   A = G (256x256/batch) fragments from global (L2-hot). 2 m-chunks.
// grid (128 n-tiles, 8 batches)
// ---------------------------------------------------------------------------
__global__ __launch_bounds__(256) void k6_out(const unsigned short* __restrict__ G,
                                              const unsigned short* __restrict__ xT,
                                              const float* __restrict__ b2,
                                              float* __restrict__ out) {
    __shared__ __align__(16) unsigned short Bs[128 * 256];  // 64 KB
    const int b  = blockIdx.y;
    const int n0 = blockIdx.x * 128;
    const int t = threadIdx.x, wave = t >> 6, lane = t & 63;
    const int wm = wave >> 1, wn = wave & 1;

    const unsigned short* Gb  = G + (size_t)b * C_ * C_;
    const unsigned short* xTb = xT + (size_t)b * N_ * C_ + (size_t)n0 * C_;
#pragma unroll
    for (int rnd = 0; rnd < 16; rnd++) {
        gl_lds16(xTb + rnd * 2048 + wave * 512 + lane * 8,
                 Bs + rnd * 2048 + wave * 512);
    }
    __syncthreads();

    const int fr = lane & 15;
    const int fk = (lane >> 4) * 8;
    const int col = lane & 15, rowq = (lane >> 4) * 4;
    float* ob = out + (size_t)b * C_ * N_;

    for (int mc = 0; mc < 2; mc++) {
        const int mbase = mc * 128;
        f32x4 acc[4][4];
#pragma unroll
        for (int i = 0; i < 4; i++)
#pragma unroll
            for (int j = 0; j < 4; j++)
#pragma unroll
                for (int r = 0; r < 4; r++) acc[i][j][r] = 0.f;

#pragma unroll
        for (int kk = 0; kk < 256; kk += 32) {
            bf16x8 af[4], bfv[4];
#pragma unroll
            for (int i = 0; i < 4; i++)
                af[i] = *(const bf16x8*)(Gb + (size_t)(mbase + wm * 64 + i * 16 + fr) * 256 + kk + fk);
#pragma unroll
            for (int j = 0; j < 4; j++)
                bfv[j] = *(const bf16x8*)(Bs + (wn * 64 + j * 16 + fr) * 256 + kk + fk);
#pragma unroll
            for (int i = 0; i < 4; i++)
#pragma unroll
                for (int j = 0; j < 4; j++)
                    acc[i][j] = mfma16(af[i], bfv[j], acc[i][j]);
        }

#pragma unroll
        for (int i = 0; i < 4; i++) {
            const int gm = mbase + wm * 64 + i * 16 + rowq;
#pragma unroll
            for (int j = 0; j < 4; j++) {
                const int gn = n0 + wn * 64 + j * 16 + col;
#pragma unroll
                for (int r = 0; r < 4; r++) {
                    const float val = fmaxf(acc[i][j][r] + b2[gm + r], 0.f);
                    ob[(size_t)(gm + r) * N_ + gn] = val;
                }
            }
        }
    }
}

// ---------------------------------------------------------------------------
extern "C" void kernel_launch(void* const* d_in, const int* in_sizes, int n_in,
                              void* d_out, int out_size, void* d_ws, size_t ws_size,
                              hipStream_t stream) {
    const float* x     = (const float*)d_in[0];
    const float* wqkv  = (const float*)d_in[1];
    const float* wproj = (const float*)d_in[2];
    const float* gamma = (const float*)d_in[3];
    const float* beta  = (const float*)d_in[4];
    const float* rmean = (const float*)d_in[5];
    const float* rvar  = (const float*)d_in[6];
    float* out = (float*)d_out;

    char* ws = (char*)d_ws;
    size_t off = 0;
    auto alloc = [&](size_t bytes) {
        void* p = ws + off;
        off += (bytes + 255) & ~(size_t)255;
        return p;
    };
    // ctx, rmaxU, rsum contiguous -> single memset clears all three.
    float*        ctx   = (float*)alloc((size_t)B_ * C_ * C_ * 4);   // 2 MiB
    unsigned int* rmaxU = (unsigned int*)alloc(2048 * 4);
    float*        rsum  = (float*)alloc(2048 * 4);
    const size_t  zero_bytes = (size_t)B_ * C_ * C_ * 4 + 2 * 2048 * 4 + 512; // incl. pad

    unsigned short* xT      = (unsigned short*)alloc((size_t)B_ * N_ * C_ * 2);  // 64 MiB
    unsigned short* kL      = (unsigned short*)alloc((size_t)B_ * C_ * N_ * 2);
    unsigned short* vvp     = (unsigned short*)alloc((size_t)B_ * C_ * N_ * 2);
    unsigned short* wqkv_bf = (unsigned short*)alloc((size_t)768 * 256 * 2);
    float* invp = (float*)alloc(256 * 4);
    float* b2p  = (float*)alloc(256 * 4);
    float* Tm   = (float*)alloc((size_t)B_ * C_ * C_ * 4);
    unsigned short* G = (unsigned short*)alloc((size_t)B_ * C_ * C_ * 2);

    hipMemsetAsync(ctx, 0, zero_bytes, stream);
    hipLaunchKernelGGL(k1_transpose, dim3(256, 4, 8), dim3(256), 0, stream, x, xT);
    hipLaunchKernelGGL(k1b_setup, dim3(193), dim3(256), 0, stream,
                       wqkv, gamma, beta, rmean, rvar, wqkv_bf, invp, b2p);
    hipLaunchKernelGGL(k2_kv, dim3(128, 8), dim3(256), 0, stream,
                       wqkv_bf + 256 * 256, xT, kL, vvp, rmaxU);
    hipLaunchKernelGGL(k4_ctx, dim3(2, 2, 64), dim3(256), 0, stream,
                       kL, vvp, rmaxU, ctx, rsum);
    hipLaunchKernelGGL(k5a_T, dim3(4, 4, 8), dim3(256), 0, stream, wproj, ctx, rsum, Tm);
    hipLaunchKernelGGL(k5b_G, dim3(4, 4, 8), dim3(256), 0, stream, Tm, wqkv, invp, G);
    hipLaunchKernelGGL(k6_out, dim3(128, 8), dim3(256), 0, stream, G, xT, b2p, out);
}

// Round 4
// 530.115 us; speedup vs baseline: 1.0109x; 1.0109x over previous
//
#include <hip/hip_runtime.h>
#include <stdint.h>

// Problem constants
#define B_   8
#define C_   256
#define N_   16384   // 128*128 spatial

typedef __attribute__((ext_vector_type(8))) short bf16x8;
typedef __attribute__((ext_vector_type(4))) float f32x4;

__device__ inline float bf2f(unsigned short h) {
    return __uint_as_float(((unsigned)h) << 16);
}
__device__ inline unsigned short f2bf(float f) {
    unsigned u = __float_as_uint(f);
    u += 0x7FFF + ((u >> 16) & 1);   // round-to-nearest-even
    return (unsigned short)(u >> 16);
}
// monotone float<->uint key for atomicMax over floats
__device__ inline unsigned fkey(float f) {
    unsigned u = __float_as_uint(f);
    return (u & 0x80000000u) ? ~u : (u | 0x80000000u);
}
__device__ inline float funkey(unsigned k) {
    unsigned u = (k & 0x80000000u) ? (k ^ 0x80000000u) : ~k;
    return __uint_as_float(u);
}

// async global->LDS, 16B per lane. LDS dest = wave-uniform base + lane*16.
__device__ inline void gl_lds16(const void* g, void* l) {
    __builtin_amdgcn_global_load_lds(
        reinterpret_cast<const __attribute__((address_space(1))) unsigned int*>(
            reinterpret_cast<uintptr_t>(g)),
        reinterpret_cast<__attribute__((address_space(3))) unsigned int*>(
            reinterpret_cast<uintptr_t>(l)),
        16, 0, 0);
}

__device__ inline f32x4 mfma16(bf16x8 a, bf16x8 b, f32x4 c) {
    return __builtin_amdgcn_mfma_f32_16x16x32_bf16(a, b, c, 0, 0, 0);
}

// ---------------------------------------------------------------------------
// K1: x [B,C,N] fp32  ->  xT [B,N,C] bf16   (64x64 tiles through LDS)
// ---------------------------------------------------------------------------
__global__ __launch_bounds__(256) void k1_transpose(const float* __restrict__ x,
                                                    unsigned short* __restrict__ xT) {
    __shared__ unsigned short tile[64][65];
    const int b = blockIdx.z, c0 = blockIdx.y * 64, n0 = blockIdx.x * 64;
    const float* xb = x + (size_t)b * C_ * N_;
    const int t = threadIdx.x;
    const int tr = t >> 4, tc4 = (t & 15) * 4;
#pragma unroll
    for (int p = 0; p < 4; p++) {
        const int i = p * 16 + tr;   // c index
        const float4 v = *(const float4*)(xb + (size_t)(c0 + i) * N_ + n0 + tc4);
        tile[i][tc4 + 0] = f2bf(v.x);
        tile[i][tc4 + 1] = f2bf(v.y);
        tile[i][tc4 + 2] = f2bf(v.z);
        tile[i][tc4 + 3] = f2bf(v.w);
    }
    __syncthreads();
    unsigned short* xTb = xT + (size_t)b * N_ * C_;
#pragma unroll
    for (int p = 0; p < 4; p++) {
        const int jj = p * 16 + tr;  // n index
        ushort4 o;
        o.x = tile[tc4 + 0][jj];
        o.y = tile[tc4 + 1][jj];
        o.z = tile[tc4 + 2][jj];
        o.w = tile[tc4 + 3][jj];
        *(ushort4*)(xTb + (size_t)(n0 + jj) * C_ + c0 + tc4) = o;
    }
}

// ---------------------------------------------------------------------------
// K1b: convert w_qkv -> bf16 (blocks 0..191), block 192 computes BN constants
// ---------------------------------------------------------------------------
__global__ __launch_bounds__(256) void k1b_setup(const float* __restrict__ wqkv,
                                                 const float* __restrict__ gamma,
                                                 const float* __restrict__ beta,
                                                 const float* __restrict__ rmean,
                                                 const float* __restrict__ rvar,
                                                 unsigned short* __restrict__ wqkv_bf,
                                                 float* __restrict__ inv,
                                                 float* __restrict__ b2) {
    const int t = threadIdx.x;
    if (blockIdx.x < 192) {
        const int base = blockIdx.x * 1024 + t * 4;
        const float4 v = *(const float4*)(wqkv + base);
        ushort4 o;
        o.x = f2bf(v.x); o.y = f2bf(v.y); o.z = f2bf(v.z); o.w = f2bf(v.w);
        *(ushort4*)(wqkv_bf + base) = o;
    } else {
        const float iv = gamma[t] * rsqrtf(rvar[t] + 1e-5f);
        inv[t] = iv;
        b2[t]  = beta[t] - rmean[t] * iv;
    }
}

// ---------------------------------------------------------------------------
// K2: KV GEMM, B-resident with XOR-swizzled LDS.
//   Bs = xT tile [128 n][256 k] bf16 = 64 KB, staged ONCE. Physical layout:
//   8-short chunk c of row r lives at chunk (c ^ (r&7)) -> conflict-free
//   ds_read_b128 (2-way max, free per m136). Staging sources the swizzled
//   global chunk per lane (gl_lds16 allows per-lane global addresses).
//   A = Wkv fragments straight from global (L2-hot). No K-loop barriers.
// grid (128 n-tiles, 8 batches), 256 thr
// ---------------------------------------------------------------------------
__global__ __launch_bounds__(256) void k2_kv(const unsigned short* __restrict__ Wkv,
                                             const unsigned short* __restrict__ xT,
                                             unsigned short* __restrict__ kL,
                                             unsigned short* __restrict__ vv,
                                             unsigned int* __restrict__ rmaxU) {
    __shared__ __align__(16) unsigned short Bs[128 * 256];  // 64 KB
    const int b  = blockIdx.y;
    const int n0 = blockIdx.x * 128;
    const int t = threadIdx.x, wave = t >> 6, lane = t & 63;
    const int wm = wave >> 1, wn = wave & 1;

    const unsigned short* xTb = xT + (size_t)b * N_ * C_ + (size_t)n0 * C_;
    // swizzled staging: lane's LDS slot (row rp, chunk lane&31) must hold
    // logical chunk (lane&31) ^ (rp&7);  rp&7 = (wave*2 + (lane>>5)) & 7.
    const int swz = ((wave * 2 + (lane >> 5)) & 7);
    const int cl  = ((lane & 31) ^ swz) * 8;
    const int rlo = wave * 2 + (lane >> 5);
#pragma unroll
    for (int rnd = 0; rnd < 16; rnd++) {
        gl_lds16(xTb + (size_t)(rnd * 8 + rlo) * 256 + cl,
                 Bs + rnd * 2048 + wave * 512);
    }
    __syncthreads();   // Bs staged; read-only afterwards

    const int fr = lane & 15;
    const int fk = (lane >> 4) * 8;
    const int col = lane & 15, rowq = (lane >> 4) * 4;
    // B-fragment row constants (per j): row, row*256, row&7
    int browoff[4], brx[4];
#pragma unroll
    for (int j = 0; j < 4; j++) {
        const int R = wn * 64 + j * 16 + fr;
        browoff[j] = R * 256;
        brx[j] = R & 7;
    }
    unsigned short* outK = kL + (size_t)b * C_ * N_;
    unsigned short* outV = vv + (size_t)b * C_ * N_;

    for (int mc = 0; mc < 4; mc++) {
        const int mbase = mc * 128;
        f32x4 acc[4][4];
#pragma unroll
        for (int i = 0; i < 4; i++)
#pragma unroll
            for (int j = 0; j < 4; j++)
#pragma unroll
                for (int r = 0; r < 4; r++) acc[i][j][r] = 0.f;

#pragma unroll
        for (int kk = 0; kk < 256; kk += 32) {
            const int ck8 = (kk + fk) >> 3;
            bf16x8 af[4], bfv[4];
#pragma unroll
            for (int i = 0; i < 4; i++)
                af[i] = *(const bf16x8*)(Wkv + (size_t)(mbase + wm * 64 + i * 16 + fr) * 256 + kk + fk);
#pragma unroll
            for (int j = 0; j < 4; j++)
                bfv[j] = *(const bf16x8*)(Bs + browoff[j] + ((ck8 ^ brx[j]) << 3));
#pragma unroll
            for (int i = 0; i < 4; i++)
#pragma unroll
                for (int j = 0; j < 4; j++)
                    acc[i][j] = mfma16(af[i], bfv[j], acc[i][j]);
        }

        if (mc < 2) {
            // k-logit rows: store bf16 + per-row max (over this n-tile) -> atomicMax
#pragma unroll
            for (int i = 0; i < 4; i++) {
                const int gm = mbase + wm * 64 + i * 16 + rowq;
#pragma unroll
                for (int r = 0; r < 4; r++) {
                    float vmax = -3.4e38f;
#pragma unroll
                    for (int j = 0; j < 4; j++) {
                        const int gn = n0 + wn * 64 + j * 16 + col;
                        const unsigned short hv = f2bf(acc[i][j][r]);
                        outK[(size_t)(gm + r) * N_ + gn] = hv;
                        vmax = fmaxf(vmax, bf2f(hv));
                    }
#pragma unroll
                    for (int o = 1; o < 16; o <<= 1)
                        vmax = fmaxf(vmax, __shfl_xor(vmax, o, 64));
                    if (col == 0)
                        atomicMax(&rmaxU[b * 256 + gm + r], fkey(vmax));
                }
            }
        } else {
#pragma unroll
            for (int i = 0; i < 4; i++) {
                const int gm = mbase - 256 + wm * 64 + i * 16 + rowq;
#pragma unroll
                for (int j = 0; j < 4; j++) {
                    const int gn = n0 + wn * 64 + j * 16 + col;
#pragma unroll
                    for (int r = 0; r < 4; r++)
                        outV[(size_t)(gm + r) * N_ + gn] = f2bf(acc[i][j][r]);
                }
            }
        }
    }
}

// ---------------------------------------------------------------------------
// K4: ctx_raw[b,c,d] += sum_n exp(k[c,n]-max_c) * v[d,n].  Split-K over n
//     (8 chunks of 2048), fp32 atomicAdd.  Also accumulates rsum[b,c].
// grid (2,2, B*8)
// ---------------------------------------------------------------------------
__global__ __launch_bounds__(256) void k4_ctx(const unsigned short* __restrict__ kL,
                                              const unsigned short* __restrict__ v,
                                              const unsigned int* __restrict__ rmaxU,
                                              float* __restrict__ ctx,
                                              float* __restrict__ rsum) {
    __shared__ __align__(16) unsigned short As[128 * 32];
    __shared__ __align__(16) unsigned short Bs[128 * 32];
    const int bz = blockIdx.z;
    const int b = bz >> 3, s = bz & 7;
    const int m0 = blockIdx.y * 128;   // c rows
    const int n0 = blockIdx.x * 128;   // d rows
    const int t = threadIdx.x, wave = t >> 6, lane = t & 63;
    const int wm = wave >> 1, wn = wave & 1;

    const unsigned short* kb = kL + (size_t)b * C_ * N_;
    const unsigned short* vb = v  + (size_t)b * C_ * N_;

    const int ch1 = wave * 64 + lane, ch2 = ch1 + 256;
    const int r1 = ch1 >> 2, q1 = ch1 & 3;
    const int r2 = ch2 >> 2, q2 = ch2 & 3;
    const float mx1 = funkey(rmaxU[b * 256 + m0 + r1]);
    const float mx2 = funkey(rmaxU[b * 256 + m0 + r2]);
    unsigned short* ldsB1 = Bs + wave * 512;
    unsigned short* ldsB2 = Bs + 2048 + wave * 512;

    f32x4 acc[4][4];
#pragma unroll
    for (int i = 0; i < 4; i++)
#pragma unroll
        for (int j = 0; j < 4; j++)
#pragma unroll
            for (int r = 0; r < 4; r++) acc[i][j][r] = 0.f;

    float sacc1 = 0.f, sacc2 = 0.f;
    const int fr = lane & 15;
    const int fk = (lane >> 4) * 8;
    const int kbase = s * 2048;

    for (int kk = kbase; kk < kbase + 2048; kk += 32) {
        __syncthreads();
        gl_lds16(vb + (size_t)(n0 + r1) * N_ + kk + q1 * 8, ldsB1);
        gl_lds16(vb + (size_t)(n0 + r2) * N_ + kk + q2 * 8, ldsB2);
        const uint4 a1 = *(const uint4*)(kb + (size_t)(m0 + r1) * N_ + kk + q1 * 8);
        const uint4 a2 = *(const uint4*)(kb + (size_t)(m0 + r2) * N_ + kk + q2 * 8);
        uint4 e1, e2;
        {
            const unsigned short* p = (const unsigned short*)&a1;
            unsigned short* o = (unsigned short*)&e1;
#pragma unroll
            for (int e = 0; e < 8; e++) {
                const float ev = __expf(bf2f(p[e]) - mx1);
                sacc1 += ev;
                o[e] = f2bf(ev);
            }
        }
        {
            const unsigned short* p = (const unsigned short*)&a2;
            unsigned short* o = (unsigned short*)&e2;
#pragma unroll
            for (int e = 0; e < 8; e++) {
                const float ev = __expf(bf2f(p[e]) - mx2);
                sacc2 += ev;
                o[e] = f2bf(ev);
            }
        }
        *(uint4*)(As + r1 * 32 + q1 * 8) = e1;
        *(uint4*)(As + r2 * 32 + q2 * 8) = e2;
        __syncthreads();
        bf16x8 af[4], bfv[4];
#pragma unroll
        for (int i = 0; i < 4; i++)
            af[i] = *(const bf16x8*)(As + (wm * 64 + i * 16 + fr) * 32 + fk);
#pragma unroll
        for (int j = 0; j < 4; j++)
            bfv[j] = *(const bf16x8*)(Bs + (wn * 64 + j * 16 + fr) * 32 + fk);
#pragma unroll
        for (int i = 0; i < 4; i++)
#pragma unroll
            for (int j = 0; j < 4; j++)
                acc[i][j] = mfma16(af[i], bfv[j], acc[i][j]);
    }

    if (blockIdx.x == 0) {
        sacc1 += __shfl_xor(sacc1, 1, 64);
        sacc1 += __shfl_xor(sacc1, 2, 64);
        sacc2 += __shfl_xor(sacc2, 1, 64);
        sacc2 += __shfl_xor(sacc2, 2, 64);
        if ((lane & 3) == 0) {
            atomicAdd(&rsum[b * 256 + m0 + r1], sacc1);
            atomicAdd(&rsum[b * 256 + m0 + r2], sacc2);
        }
    }

    float* cb = ctx + (size_t)b * C_ * C_;
    const int col = lane & 15, rowq = (lane >> 4) * 4;
#pragma unroll
    for (int i = 0; i < 4; i++) {
        const int gc = m0 + wm * 64 + i * 16 + rowq;
#pragma unroll
        for (int j = 0; j < 4; j++) {
            const int gd = n0 + wn * 64 + j * 16 + col;
#pragma unroll
            for (int r = 0; r < 4; r++)
                atomicAdd(&cb[(size_t)(gc + r) * C_ + gd], acc[i][j][r]);
        }
    }
}

// ---------------------------------------------------------------------------
// K5a: T[b,o,c] = (sum_d Wp[o,d]*ctx[b,c,d]) / rsum[b,c]   (fp32 tiled)
// grid (4,4,8) : 64x64 tiles
// ---------------------------------------------------------------------------
__global__ __launch_bounds__(256) void k5a_T(const float* __restrict__ Wp,
                                             const float* __restrict__ ctx,
                                             const float* __restrict__ rsum,
                                             float* __restrict__ T) {
    __shared__ float Asm[64][65];
    __shared__ float Bsm[64][65];
    const int b = blockIdx.z;
    const int o0 = blockIdx.y * 64, c0 = blockIdx.x * 64;
    const int t = threadIdx.x;
    const int tm = t >> 4, tn = t & 15;
    const int lc4 = tn * 4;
    float acc[4][4] = {};
    const float* cb = ctx + (size_t)b * C_ * C_;
    for (int kk = 0; kk < 256; kk += 64) {
        __syncthreads();
#pragma unroll
        for (int p = 0; p < 4; p++) {
            const int r = p * 16 + tm;
            const float4 av = *(const float4*)(Wp + (size_t)(o0 + r) * C_ + kk + lc4);
            Asm[r][lc4] = av.x; Asm[r][lc4 + 1] = av.y; Asm[r][lc4 + 2] = av.z; Asm[r][lc4 + 3] = av.w;
            const float4 bv = *(const float4*)(cb + (size_t)(c0 + r) * C_ + kk + lc4);
            Bsm[r][lc4] = bv.x; Bsm[r][lc4 + 1] = bv.y; Bsm[r][lc4 + 2] = bv.z; Bsm[r][lc4 + 3] = bv.w;
        }
        __syncthreads();
        for (int k = 0; k < 64; k++) {
            float a_[4], b_[4];
#pragma unroll
            for (int i = 0; i < 4; i++) a_[i] = Asm[tm * 4 + i][k];
#pragma unroll
            for (int j = 0; j < 4; j++) b_[j] = Bsm[tn * 4 + j][k];
#pragma unroll
            for (int i = 0; i < 4; i++)
#pragma unroll
                for (int j = 0; j < 4; j++) acc[i][j] += a_[i] * b_[j];
        }
    }
    float isv[4];
#pragma unroll
    for (int j = 0; j < 4; j++) isv[j] = 1.f / rsum[b * 256 + c0 + tn * 4 + j];
#pragma unroll
    for (int i = 0; i < 4; i++)
#pragma unroll
        for (int j = 0; j < 4; j++)
            T[((size_t)b * C_ + o0 + tm * 4 + i) * C_ + c0 + tn * 4 + j] = acc[i][j] * isv[j];
}

// ---------------------------------------------------------------------------
// K5b: G[b,o,j] = inv[o] * sum_c T[b,o,c]*Wq[c,j]   -> bf16  (fp32 tiled)
// grid (4,4,8)
// ---------------------------------------------------------------------------
__global__ __launch_bounds__(256) void k5b_G(const float* __restrict__ Tm,
                                             const float* __restrict__ Wq,
                                             const float* __restrict__ inv,
                                             unsigned short* __restrict__ G) {
    __shared__ float Asm[64][65];   // T rows o, cols c (k)
    __shared__ float Bsm[64][65];   // Wq rows c (k), cols j
    const int b = blockIdx.z;
    const int o0 = blockIdx.y * 64, j0 = blockIdx.x * 64;
    const int t = threadIdx.x;
    const int tm = t >> 4, tn = t & 15;
    const int lc4 = tn * 4;
    float acc[4][4] = {};
    const float* Tb = Tm + (size_t)b * C_ * C_;
    for (int kk = 0; kk < 256; kk += 64) {
        __syncthreads();
#pragma unroll
        for (int p = 0; p < 4; p++) {
            const int r = p * 16 + tm;
            const float4 av = *(const float4*)(Tb + (size_t)(o0 + r) * C_ + kk + lc4);
            Asm[r][lc4] = av.x; Asm[r][lc4 + 1] = av.y; Asm[r][lc4 + 2] = av.z; Asm[r][lc4 + 3] = av.w;
            const float4 bv = *(const float4*)(Wq + (size_t)(kk + r) * C_ + j0 + lc4);
            Bsm[r][lc4] = bv.x; Bsm[r][lc4 + 1] = bv.y; Bsm[r][lc4 + 2] = bv.z; Bsm[r][lc4 + 3] = bv.w;
        }
        __syncthreads();
        for (int k = 0; k < 64; k++) {
            float a_[4], b_[4];
#pragma unroll
            for (int i = 0; i < 4; i++) a_[i] = Asm[tm * 4 + i][k];
#pragma unroll
            for (int j = 0; j < 4; j++) b_[j] = Bsm[k][tn * 4 + j];
#pragma unroll
            for (int i = 0; i < 4; i++)
#pragma unroll
                for (int j = 0; j < 4; j++) acc[i][j] += a_[i] * b_[j];
        }
    }
#pragma unroll
    for (int i = 0; i < 4; i++) {
        const float iv = inv[o0 + tm * 4 + i];
#pragma unroll
        for (int j = 0; j < 4; j++)
            G[((size_t)b * C_ + o0 + tm * 4 + i) * C_ + j0 + tn * 4 + j] = f2bf(acc[i][j] * iv);
    }
}

// ---------------------------------------------------------------------------
// K6: out[b,o,n] = relu( sum_j G[b,o,j]*xT[b,n,j] + b2[o] )  fp32 out
//   B-resident + XOR-swizzled Bs (same scheme as K2). A = G from global.
// grid (128 n-tiles, 8 batches)
// ---------------------------------------------------------------------------
__global__ __launch_bounds__(256) void k6_out(const unsigned short* __restrict__ G,
                                              const unsigned short* __restrict__ xT,
                                              const float* __restrict__ b2,
                                              float* __restrict__ out) {
    __shared__ __align__(16) unsigned short Bs[128 * 256];  // 64 KB
    const int b  = blockIdx.y;
    const int n0 = blockIdx.x * 128;
    const int t = threadIdx.x, wave = t >> 6, lane = t & 63;
    const int wm = wave >> 1, wn = wave & 1;

    const unsigned short* Gb  = G + (size_t)b * C_ * C_;
    const unsigned short* xTb = xT + (size_t)b * N_ * C_ + (size_t)n0 * C_;
    const int swz = ((wave * 2 + (lane >> 5)) & 7);
    const int cl  = ((lane & 31) ^ swz) * 8;
    const int rlo = wave * 2 + (lane >> 5);
#pragma unroll
    for (int rnd = 0; rnd < 16; rnd++) {
        gl_lds16(xTb + (size_t)(rnd * 8 + rlo) * 256 + cl,
                 Bs + rnd * 2048 + wave * 512);
    }
    __syncthreads();

    const int fr = lane & 15;
    const int fk = (lane >> 4) * 8;
    const int col = lane & 15, rowq = (lane >> 4) * 4;
    int browoff[4], brx[4];
#pragma unroll
    for (int j = 0; j < 4; j++) {
        const int R = wn * 64 + j * 16 + fr;
        browoff[j] = R * 256;
        brx[j] = R & 7;
    }
    float* ob = out + (size_t)b * C_ * N_;

    for (int mc = 0; mc < 2; mc++) {
        const int mbase = mc * 128;
        f32x4 acc[4][4];
#pragma unroll
        for (int i = 0; i < 4; i++)
#pragma unroll
            for (int j = 0; j < 4; j++)
#pragma unroll
                for (int r = 0; r < 4; r++) acc[i][j][r] = 0.f;

#pragma unroll
        for (int kk = 0; kk < 256; kk += 32) {
            const int ck8 = (kk + fk) >> 3;
            bf16x8 af[4], bfv[4];
#pragma unroll
            for (int i = 0; i < 4; i++)
                af[i] = *(const bf16x8*)(Gb + (size_t)(mbase + wm * 64 + i * 16 + fr) * 256 + kk + fk);
#pragma unroll
            for (int j = 0; j < 4; j++)
                bfv[j] = *(const bf16x8*)(Bs + browoff[j] + ((ck8 ^ brx[j]) << 3));
#pragma unroll
            for (int i = 0; i < 4; i++)
#pragma unroll
                for (int j = 0; j < 4; j++)
                    acc[i][j] = mfma16(af[i], bfv[j], acc[i][j]);
        }

#pragma unroll
        for (int i = 0; i < 4; i++) {
            const int gm = mbase + wm * 64 + i * 16 + rowq;
#pragma unroll
            for (int j = 0; j < 4; j++) {
                const int gn = n0 + wn * 64 + j * 16 + col;
#pragma unroll
                for (int r = 0; r < 4; r++) {
                    const float val = fmaxf(acc[i][j][r] + b2[gm + r], 0.f);
                    ob[(size_t)(gm + r) * N_ + gn] = val;
                }
            }
        }
    }
}

// ---------------------------------------------------------------------------
extern "C" void kernel_launch(void* const* d_in, const int* in_sizes, int n_in,
                              void* d_out, int out_size, void* d_ws, size_t ws_size,
                              hipStream_t stream) {
    const float* x     = (const float*)d_in[0];
    const float* wqkv  = (const float*)d_in[1];
    const float* wproj = (const float*)d_in[2];
    const float* gamma = (const float*)d_in[3];
    const float* beta  = (const float*)d_in[4];
    const float* rmean = (const float*)d_in[5];
    const float* rvar  = (const float*)d_in[6];
    float* out = (float*)d_out;

    char* ws = (char*)d_ws;
    size_t off = 0;
    auto alloc = [&](size_t bytes) {
        void* p = ws + off;
        off += (bytes + 255) & ~(size_t)255;
        return p;
    };
    // ctx, rmaxU, rsum contiguous -> single memset clears all three.
    float*        ctx   = (float*)alloc((size_t)B_ * C_ * C_ * 4);   // 2 MiB
    unsigned int* rmaxU = (unsigned int*)alloc(2048 * 4);
    float*        rsum  = (float*)alloc(2048 * 4);
    const size_t  zero_bytes = (size_t)B_ * C_ * C_ * 4 + 2 * 2048 * 4 + 512; // incl. pad

    unsigned short* xT      = (unsigned short*)alloc((size_t)B_ * N_ * C_ * 2);  // 64 MiB
    unsigned short* kL      = (unsigned short*)alloc((size_t)B_ * C_ * N_ * 2);
    unsigned short* vvp     = (unsigned short*)alloc((size_t)B_ * C_ * N_ * 2);
    unsigned short* wqkv_bf = (unsigned short*)alloc((size_t)768 * 256 * 2);
    float* invp = (float*)alloc(256 * 4);
    float* b2p  = (float*)alloc(256 * 4);
    float* Tm   = (float*)alloc((size_t)B_ * C_ * C_ * 4);
    unsigned short* G = (unsigned short*)alloc((size_t)B_ * C_ * C_ * 2);

    hipMemsetAsync(ctx, 0, zero_bytes, stream);
    hipLaunchKernelGGL(k1_transpose, dim3(256, 4, 8), dim3(256), 0, stream, x, xT);
    hipLaunchKernelGGL(k1b_setup, dim3(193), dim3(256), 0, stream,
                       wqkv, gamma, beta, rmean, rvar, wqkv_bf, invp, b2p);
    hipLaunchKernelGGL(k2_kv, dim3(128, 8), dim3(256), 0, stream,
                       wqkv_bf + 256 * 256, xT, kL, vvp, rmaxU);
    hipLaunchKernelGGL(k4_ctx, dim3(2, 2, 64), dim3(256), 0, stream,
                       kL, vvp, rmaxU, ctx, rsum);
    hipLaunchKernelGGL(k5a_T, dim3(4, 4, 8), dim3(256), 0, stream, wproj, ctx, rsum, Tm);
    hipLaunchKernelGGL(k5b_G, dim3(4, 4, 8), dim3(256), 0, stream, Tm, wqkv, invp, G);
    hipLaunchKernelGGL(k6_out, dim3(128, 8), dim3(256), 0, stream, G, xT, b2p, out);
}